// Round 1
// baseline (204.392 us; speedup 1.0000x reference)
//
#include <hip/hip_runtime.h>

typedef float v2f __attribute__((ext_vector_type(2)));
typedef float v4f __attribute__((ext_vector_type(4)));   // builtin-friendly float4

// Forced packed fp32 (full-rate on CDNA).
__device__ __forceinline__ v2f pk_fma(v2f a, v2f b, v2f c) {
    v2f d;
    asm("v_pk_fma_f32 %0, %1, %2, %3" : "=v"(d) : "v"(a), "v"(b), "v"(c));
    return d;
}
__device__ __forceinline__ v2f pk_mul(v2f a, v2f b) {
    v2f d;
    asm("v_pk_mul_f32 %0, %1, %2" : "=v"(d) : "v"(a), "v"(b));
    return d;
}

// band(x1) = (tanh(100(x1-0.1)) - tanh(100(x1+0.1)) + 2)/2  (even in x1)
//          = 1 - S * rcp(0.5*e^{200|x1|} + K),  S=sinh(20)==cosh(20) in fp32
// One v_exp_f32 + one v_rcp_f32. inf -> 1 (correct saturation); NaN -> NaN.
__device__ __forceinline__ float band(float x1) {
    const float S = 2.4258257e8f;
    float t = __builtin_fabsf(x1);
    float F = __builtin_amdgcn_exp2f(288.53900817779268f * t);  // e^{200|x1|}
    float r = __builtin_amdgcn_rcpf(fmaf(0.5f, F, S));
    return fmaf(-S, r, 1.0f);
}

// Copy-shaped: persistent grid-stride loop, 4 dense 16B NT load streams per
// iteration, packed recurrence, NT 8B stores.
// Occupancy probe vs prior 8-stream version: weights live in SGPRs (not 20
// VGPRs of broadcast pairs), ld[] halved, __launch_bounds__(256,8) caps the
// allocator at 64 VGPR -> 8 waves/SIMD (was ~4 at >64 VGPR per the 64/128/256
// occupancy cliff). Traffic identical.
// Coverage exact: 2048 blk * 256 thr * 4 streams * 4 iters = 2^23 float4s = B/2.
__global__ void __launch_bounds__(256, 8)
dynsys_kernel(const v4f* __restrict__ x, const float* __restrict__ ws,
              v2f* __restrict__ out, int n4) {
    const int tid    = blockIdx.x * 256 + threadIdx.x;
    const int nthr   = gridDim.x * 256;        // dense-stream stride
    const int per_it = nthr * 4;               // float4s consumed per iteration

    // Wave-uniform weights: constant-indexed, uniform address -> s_load,
    // stays in SGPRs. The -w*x1 term uses the fma negate modifier on the
    // SGPR operand: numerically identical to the old packed wn form.
    float w[10];
#pragma unroll
    for (int k = 0; k < 10; ++k) w[k] = ws[k];
    const v2f mone = {-1.0f, -1.0f};
    const v2f cn01 = {-0.1f, -0.1f};

    for (int base = tid; base < n4; base += per_it) {
        v4f ld[4];
#pragma unroll
        for (int k = 0; k < 4; ++k)
            ld[k] = __builtin_nontemporal_load(&x[base + k * nthr]);

#pragma unroll
        for (int k = 0; k < 4; ++k) {
            v2f a0 = {ld[k].x, ld[k].z};
            v2f a1 = {ld[k].y, ld[k].w};
#pragma unroll
            for (int s = 0; s < 10; ++s) {
                v2f na0 = pk_fma(cn01, a1, a0);   // x0 - 0.1*x1
                v2f t   = pk_fma(a0, a0, mone);   // x0^2 - 1
                v2f u   = pk_mul(a0, t);          // x0^3 - x0
                v2f d;                             // ... - w*x1 (scalar fma, SGPR w)
                d.x = fmaf(-w[s], a1.x, u.x);
                d.y = fmaf(-w[s], a1.y, u.y);
                a1  = pk_fma(cn01, d, a1);        // x1 - 0.1*d
                a0  = na0;
            }
            v2f r = {band(a1.x), band(a1.y)};
            __builtin_nontemporal_store(r, &out[base + k * nthr]);
        }
    }
}

extern "C" void kernel_launch(void* const* d_in, const int* in_sizes, int n_in,
                              void* d_out, int out_size, void* d_ws, size_t ws_size,
                              hipStream_t stream) {
    const v4f*  x  = (const v4f*)d_in[0];    // [B,2] f32 = B/2 float4s
    const float* ws = (const float*)d_in[1]; // [10] f32
    v2f* out = (v2f*)d_out;                  // [B] f32 = B/2 float2s

    int n4 = in_sizes[0] / 4;                // B/2 = 2^23 float4s
    // 2048 blocks * 256 thr = 2^19 threads; *4 streams *4 iters = 2^23 exact.
    dynsys_kernel<<<2048, 256, 0, stream>>>(x, ws, out, n4);
}